// Round 10
// baseline (68.651 us; speedup 1.0000x reference)
//
#include <hip/hip_runtime.h>
#include <hip/hip_bf16.h>
#include <math.h>

typedef __attribute__((ext_vector_type(4))) float  f32x4;
typedef __attribute__((ext_vector_type(8))) __bf16 bf16x8;
typedef __attribute__((ext_vector_type(4))) __bf16 bf16x4;

#define BN_EPS 1e-5f

__device__ __forceinline__ void gload16(const void* g, void* l) {
    __builtin_amdgcn_global_load_lds(
        (const __attribute__((address_space(1))) unsigned int*)g,
        (__attribute__((address_space(3))) unsigned int*)l, 16, 0, 0);
}

// ---------- fused: x transpose->bf16 (blocks 0..4095) + W->bf16 / BN prep (blocks 4096..4607) ----------
__global__ __launch_bounds__(256) void prep_transpose_kernel(
    const float* __restrict__ x, __bf16* __restrict__ xt,
    const float* __restrict__ W, const float* __restrict__ gamma,
    const float* __restrict__ beta, const float* __restrict__ rmean,
    const float* __restrict__ rvar, __bf16* __restrict__ Wb,
    float* __restrict__ sc, float* __restrict__ bs)
{
    __shared__ float lt[64][65];
    const int t = threadIdx.x;
    const int bid = blockIdx.x;

    if (bid >= 4096) {
        const int b2 = bid - 4096;            // 0..511
        const int t2 = b2 * 256 + t;
        const int idx = t2 * 4;               // covers 524288 exactly
        f32x4 v = *(const f32x4*)(W + idx);
        bf16x4 o;
        o[0] = (__bf16)v[0]; o[1] = (__bf16)v[1];
        o[2] = (__bf16)v[2]; o[3] = (__bf16)v[3];
        *(bf16x4*)(Wb + idx) = o;
        if (b2 < 2) {
            int ch = b2 * 256 + t;
            float s = gamma[ch] * rsqrtf(rvar[ch] + BN_EPS);
            sc[ch] = s;
            bs[ch] = beta[ch] - rmean[ch] * s;
        }
        return;
    }

    const int b = bid >> 8;
    const int w = bid & 255;
    const int c0  = (w & 15) * 64;
    const int hw0 = (w >> 4) * 64;

    // read phase: [64c][64hw] fp32 tile into LDS (coalesced f32x4)
    const int cl = t >> 4;             // 0..15
    const int q  = (t & 15) * 4;       // 0..60
    const float* src = x + (((size_t)(b * 1024 + c0 + cl)) << 10) + hw0 + q;
    #pragma unroll
    for (int i = 0; i < 4; ++i) {
        f32x4 v = *(const f32x4*)(src + ((size_t)i << 14));   // +16 c-rows
        int c = cl + i * 16;
        lt[c][q + 0] = v[0]; lt[c][q + 1] = v[1];
        lt[c][q + 2] = v[2]; lt[c][q + 3] = v[3];
    }
    __syncthreads();

    // write phase: thread -> one bf16x8 (8 channels of one hw row), 16B stores.
    const int hwl = t >> 3;            // 0..31
    const int oct = (t & 7) * 8;       // c sub-base 0..56
    #pragma unroll
    for (int half = 0; half < 2; ++half) {
        const int hw = hwl + half * 32;
        bf16x8 v;
        #pragma unroll
        for (int i = 0; i < 8; ++i)
            v[i] = (__bf16)lt[oct + i][hw];
        *(bf16x8*)(xt + (((size_t)(b * 1024 + hw0 + hw)) << 10) + c0 + oct) = v;
    }
}

// ---------- GEMM (128x128 tile, BK=64) + BN + Mish, writes y to out[ch 1536..2047] ----------
// kk-split frag loads halve live frag registers -> fits 128 VGPR -> 4 blocks/CU.
__global__ __launch_bounds__(256, 4) void gemm_kernel(
    const __bf16* __restrict__ Wb,   // [512][1024]
    const __bf16* __restrict__ xt,   // [16][1024 hw][1024 c]
    const float* __restrict__ sc, const float* __restrict__ bs,
    float* __restrict__ out)
{
    __shared__ __align__(16) char lds[32768];
    char* const Alds = lds;            // [128 rows][64 k] bf16, slot-swizzled
    char* const Blds = lds + 16384;

    const int t  = threadIdx.x;
    // XCD-chunked swizzle (T1): bijective, each XCD owns 2 whole batches ->
    // B working set (2x2MB) + W (1MB) ~ L2-resident.  f&7 = b>>1.
    const int f  = blockIdx.x + 4 * (blockIdx.y + 8 * blockIdx.z);  // 0..511
    const int f2 = (f & 7) * 64 + (f >> 3);
    const int o0  = (f2 & 3) * 128;          // 0..384
    const int hw0 = ((f2 >> 2) & 7) * 128;   // 0..896
    const int b   = f2 >> 5;                 // 0..15

    // staging: thread t loads 16B for LDS-linear slot (row=t/8, slot=t%8);
    // global source slot pre-swizzled so lds[row][s] holds logical slot s^(row&7)
    const int srow = t >> 3;
    const int sswz = ((t & 7) ^ ((t >> 3) & 7)) * 16;
    const char* Ag = (const char*)Wb + (((size_t)(o0 + srow)) << 11) + sswz;
    const char* Bg = (const char*)xt + ((size_t)b << 21)
                   + (((size_t)(hw0 + srow)) << 11) + sswz;
    char* Al = Alds + t * 16;
    char* Bl = Blds + t * 16;

    const int l  = t & 63;
    const int lr = l & 15;             // frag row-within-16
    const int lk = l >> 4;             // frag k-block 0..3
    const int wm = (t >> 6) & 1;       // wave m (2x2 waves, 64x64 each)
    const int wn = t >> 7;             // wave n

    int aoff[4][2], boff[4][2];
    #pragma unroll
    for (int i = 0; i < 4; ++i)
        #pragma unroll
        for (int kk = 0; kk < 2; ++kk) {
            int ra = wm * 64 + i * 16 + lr;
            int rb = wn * 64 + i * 16 + lr;
            int s  = lk + kk * 4;
            aoff[i][kk] = ra * 128 + ((s ^ (ra & 7)) * 16);
            boff[i][kk] = rb * 128 + ((s ^ (rb & 7)) * 16);
        }

    f32x4 acc[4][4] = {};

    for (int ks = 0; ks < 16; ++ks) {
        __syncthreads();
        const int kb = ks * 128;       // 64 bf16 per K-step
        #pragma unroll
        for (int i = 0; i < 4; ++i) {
            gload16(Ag + (i << 16) + kb, Al + (i << 12));
            gload16(Bg + (i << 16) + kb, Bl + (i << 12));
        }
        __syncthreads();
        #pragma unroll
        for (int kk = 0; kk < 2; ++kk) {
            bf16x8 af[4], bfr[4];
            #pragma unroll
            for (int i = 0; i < 4; ++i)
                af[i]  = *(const bf16x8*)(Alds + aoff[i][kk]);
            #pragma unroll
            for (int j = 0; j < 4; ++j)
                bfr[j] = *(const bf16x8*)(Blds + boff[j][kk]);
            #pragma unroll
            for (int i = 0; i < 4; ++i)
                #pragma unroll
                for (int j = 0; j < 4; ++j)
                    acc[i][j] = __builtin_amdgcn_mfma_f32_16x16x32_bf16(
                        af[i], bfr[j], acc[i][j], 0, 0, 0);
        }
    }

    // epilogue: BN + Mish, store to out[b][1536+o][hw]
    // D frag mapping: row(m) = lk*4 + reg, col(n) = lr  [m89-verified]
    const size_t outbase = (((size_t)b * 2048 + 1536) << 10);
    #pragma unroll
    for (int i = 0; i < 4; ++i) {
        const int ob = o0 + wm * 64 + i * 16 + lk * 4;
        const f32x4 s4 = *(const f32x4*)(sc + ob);
        const f32x4 b4 = *(const f32x4*)(bs + ob);
        #pragma unroll
        for (int r = 0; r < 4; ++r) {
            float* orow = out + outbase + (((size_t)(ob + r)) << 10)
                        + hw0 + wn * 64 + lr;
            #pragma unroll
            for (int j = 0; j < 4; ++j) {
                float v = acc[i][j][r] * s4[r] + b4[r];
                // mish(v) = v * tanh(softplus(v)) = v * t(t+2)/(t(t+2)+2), t=e^v
                float e   = __expf(fminf(v, 15.0f));
                float num = e * (e + 2.0f);
                orow[j * 16] = v * (num / (num + 2.0f));
            }
        }
    }
}

// ---------- SPP pools: m5=pool5(y), m9=pool5(m5), m13=pool5(m9) ----------
// XCD-affinity: id&7 = b>>1, matching the GEMM swizzle, so y-reads hit the
// L2 that just wrote them. 2 channels per block.
__global__ __launch_bounds__(256) void pool_kernel(float* __restrict__ out)
{
    __shared__ float A[32][33];
    __shared__ float B[32][33];
    const int t  = threadIdx.x;
    const int id = blockIdx.x;        // 0..4095
    const int x8 = id & 7;
    const int j  = id >> 3;           // 0..511
    const int b  = 2 * x8 + (j >> 8);
    const int o2 = (j & 255) * 2;
    const int r  = t >> 3;            // row 0..31
    const int c0 = (t & 7) * 4;       // col base

    for (int ci = 0; ci < 2; ++ci) {
        const int o = o2 + ci;
        const size_t ybase = ((size_t)(b * 2048 + 1536 + o)) << 10;
        f32x4 v = *(const f32x4*)(out + ybase + t * 4);
        A[r][c0] = v[0]; A[r][c0 + 1] = v[1]; A[r][c0 + 2] = v[2]; A[r][c0 + 3] = v[3];
        __syncthreads();

        for (int p = 0; p < 3; ++p) {
            float wv[8];
            #pragma unroll
            for (int k = 0; k < 8; ++k) {
                int cc = c0 - 2 + k;
                wv[k] = (cc >= 0 && cc < 32) ? A[r][cc] : -INFINITY;
            }
            #pragma unroll
            for (int q = 0; q < 4; ++q) {
                float h = fmaxf(fmaxf(fmaxf(wv[q], wv[q + 1]), fmaxf(wv[q + 2], wv[q + 3])), wv[q + 4]);
                B[r][c0 + q] = h;
            }
            __syncthreads();
            f32x4 m;
            m[0] = m[1] = m[2] = m[3] = -INFINITY;
            #pragma unroll
            for (int k = 0; k < 5; ++k) {
                int rr = r - 2 + k;
                if (rr >= 0 && rr < 32) {
                    m[0] = fmaxf(m[0], B[rr][c0]);
                    m[1] = fmaxf(m[1], B[rr][c0 + 1]);
                    m[2] = fmaxf(m[2], B[rr][c0 + 2]);
                    m[3] = fmaxf(m[3], B[rr][c0 + 3]);
                }
            }
            A[r][c0] = m[0]; A[r][c0 + 1] = m[1]; A[r][c0 + 2] = m[2]; A[r][c0 + 3] = m[3];
            const size_t obase = ((size_t)(b * 2048 + (2 - p) * 512 + o)) << 10;
            *(f32x4*)(out + obase + t * 4) = m;
            __syncthreads();
        }
    }
}

extern "C" void kernel_launch(void* const* d_in, const int* in_sizes, int n_in,
                              void* d_out, int out_size, void* d_ws, size_t ws_size,
                              hipStream_t stream)
{
    const float* x     = (const float*)d_in[0];  // [16,1024,32,32]
    const float* W     = (const float*)d_in[1];  // [512,1024]
    const float* gamma = (const float*)d_in[2];
    const float* beta  = (const float*)d_in[3];
    const float* rmean = (const float*)d_in[4];
    const float* rvar  = (const float*)d_in[5];
    float* out = (float*)d_out;                  // [16,2048,32,32]
    char*  ws  = (char*)d_ws;

    __bf16* xt = (__bf16*)ws;                    // 33554432 B: [16][1024 hw][1024 c]
    __bf16* Wb = (__bf16*)(ws + 33554432);       //  1048576 B: [512][1024]
    float*  sc = (float*)(ws + 34603008);        //     2048 B
    float*  bs = (float*)(ws + 34605056);        //     2048 B

    prep_transpose_kernel<<<4608, 256, 0, stream>>>(x, xt, W, gamma, beta, rmean, rvar, Wb, sc, bs);
    gemm_kernel<<<dim3(4, 8, 16), 256, 0, stream>>>(Wb, xt, sc, bs, out);
    pool_kernel<<<4096, 256, 0, stream>>>(out);
}

// Round 11
// 63.987 us; speedup vs baseline: 1.0729x; 1.0729x over previous
//
#include <hip/hip_runtime.h>
#include <hip/hip_bf16.h>
#include <math.h>

typedef __attribute__((ext_vector_type(4))) float  f32x4;
typedef __attribute__((ext_vector_type(8))) __bf16 bf16x8;
typedef __attribute__((ext_vector_type(4))) __bf16 bf16x4;

#define BN_EPS 1e-5f

__device__ __forceinline__ void gload16(const void* g, void* l) {
    __builtin_amdgcn_global_load_lds(
        (const __attribute__((address_space(1))) unsigned int*)g,
        (__attribute__((address_space(3))) unsigned int*)l, 16, 0, 0);
}

// ---------- prep: W fp32 -> bf16, BN scale/bias ----------
__global__ __launch_bounds__(256) void prep_kernel(
    const float* __restrict__ W, const float* __restrict__ gamma,
    const float* __restrict__ beta, const float* __restrict__ rmean,
    const float* __restrict__ rvar, __bf16* __restrict__ Wb,
    float* __restrict__ sc, float* __restrict__ bs)
{
    int t = blockIdx.x * 256 + threadIdx.x;   // 0..131071
    int idx = t * 4;                           // covers 524288 exactly
    f32x4 v = *(const f32x4*)(W + idx);
    bf16x4 o;
    o[0] = (__bf16)v[0]; o[1] = (__bf16)v[1];
    o[2] = (__bf16)v[2]; o[3] = (__bf16)v[3];
    *(bf16x4*)(Wb + idx) = o;
    if (t < 512) {
        float s = gamma[t] * rsqrtf(rvar[t] + BN_EPS);
        sc[t] = s;
        bs[t] = beta[t] - rmean[t] * s;
    }
}

// ---------- GEMM (128x128 tile, BK=64) reading x fp32 DIRECTLY + BN + Mish ----------
// B staged via gload16 in natural [64c][128hw] fp32 layout (granule-XOR-swizzled
// source, rule 21); B-frags read as 4x ds_read2_b32 (k along c) + bf16 cast at
// frag time (same RNE rounding as the old xt path -> identical values).
__global__ __launch_bounds__(256, 3) void gemm_kernel(
    const __bf16* __restrict__ Wb,   // [512][1024] bf16
    const float* __restrict__ x,     // [16][1024 c][1024 hw] fp32
    const float* __restrict__ sc, const float* __restrict__ bs,
    float* __restrict__ out)
{
    __shared__ __align__(16) char lds[49152];
    char* const Alds = lds;            // [128 o][64 c] bf16, slot-swizzled (16 KB)
    char* const Blds = lds + 16384;    // [64 c][32 granules x 16B] fp32, granule-swizzled (32 KB)

    const int t  = threadIdx.x;
    // XCD-chunked swizzle (T1): f&7 = b>>1 (2 batches per XCD).
    const int f  = blockIdx.x + 4 * (blockIdx.y + 8 * blockIdx.z);  // 0..511
    const int f2 = (f & 7) * 64 + (f >> 3);
    const int o0  = (f2 & 3) * 128;          // 0..384
    const int hw0 = ((f2 >> 2) & 7) * 128;   // 0..896
    const int b   = f2 >> 5;                 // 0..15

    // ---- A staging (r7-proven): LDS linear, source slot pre-swizzled
    const int srow = t >> 3;
    const int sswz = ((t & 7) ^ ((t >> 3) & 7)) * 16;
    const char* Ag = (const char*)Wb + (((size_t)(o0 + srow)) << 11) + sswz;
    char* Al = Alds + t * 16;

    // ---- B staging: granule g = r*256+t -> (c = g>>5, phys slot sp = g&31);
    // logical slot s = sp ^ swz(c), swz(c) = ((c>>3)&3)<<2. LDS dest linear.
    int srcoff[8];
    #pragma unroll
    for (int r = 0; r < 8; ++r) {
        int g = r * 256 + t;
        int c = g >> 5, sp = g & 31;
        int s = sp ^ (((c >> 3) & 3) << 2);
        srcoff[r] = c * 1024 + s * 4;          // float offset within [64c][1024hw] slice
    }
    char* Bl = Blds + t * 16;
    const float* xb = x + ((size_t)b << 20) + hw0;

    const int l  = t & 63;
    const int lr = l & 15;             // frag col-within-16
    const int lk = l >> 4;             // k-oct 0..3
    const int wm = (t >> 6) & 1;       // wave m (2x2 waves, 64x64 each)
    const int wn = t >> 7;             // wave n

    int aoff[4][2];
    #pragma unroll
    for (int i = 0; i < 4; ++i)
        #pragma unroll
        for (int kk = 0; kk < 2; ++kk) {
            int ra = wm * 64 + i * 16 + lr;
            int s  = lk + kk * 4;
            aoff[i][kk] = ra * 128 + ((s ^ (ra & 7)) * 16);
        }
    // B-frag column offsets: n = wn*64 + j*16 + lr; swz reduces to (lk&3)<<2.
    int noff[4];
    #pragma unroll
    for (int j = 0; j < 4; ++j) {
        int n = wn * 64 + j * 16 + lr;
        noff[j] = ((((n >> 2) ^ ((lk & 3) << 2))) << 4) + ((n & 3) << 2);
    }

    f32x4 acc[4][4] = {};

    for (int ks = 0; ks < 16; ++ks) {
        __syncthreads();
        const int kb = ks * 128;       // A byte offset (64 bf16)
        #pragma unroll
        for (int i = 0; i < 4; ++i)
            gload16(Ag + (i << 16) + kb, Al + (i << 12));
        const float* xk = xb + ks * 65536;   // 64 c-rows per K-step
        #pragma unroll
        for (int r = 0; r < 8; ++r)
            gload16(xk + srcoff[r], Bl + (r << 12));
        __syncthreads();

        #pragma unroll
        for (int kk = 0; kk < 2; ++kk) {
            bf16x8 af[4], bfr[4];
            #pragma unroll
            for (int i = 0; i < 4; ++i)
                af[i] = *(const bf16x8*)(Alds + aoff[i][kk]);
            #pragma unroll
            for (int j = 0; j < 4; ++j) {
                const char* pb = Blds + (kk << 14) + (lk << 12) + noff[j];
                bf16x8 ffr;
                #pragma unroll
                for (int p = 0; p < 4; ++p) {
                    const float* pf = (const float*)(pb + (p << 10));
                    float f0 = pf[0];      // k = 2p   (row c)
                    float f1 = pf[128];    // k = 2p+1 (row c+1, +512 B)
                    ffr[2 * p]     = (__bf16)f0;
                    ffr[2 * p + 1] = (__bf16)f1;
                }
                bfr[j] = ffr;
            }
            #pragma unroll
            for (int i = 0; i < 4; ++i)
                #pragma unroll
                for (int j = 0; j < 4; ++j)
                    acc[i][j] = __builtin_amdgcn_mfma_f32_16x16x32_bf16(
                        af[i], bfr[j], acc[i][j], 0, 0, 0);
        }
    }

    // epilogue: BN + Mish, store y to out[b][1536+o][hw]
    // D frag mapping: row(m) = lk*4 + reg, col(n) = lr  [m89-verified]
    const size_t outbase = (((size_t)b * 2048 + 1536) << 10);
    #pragma unroll
    for (int i = 0; i < 4; ++i) {
        const int ob = o0 + wm * 64 + i * 16 + lk * 4;
        const f32x4 s4 = *(const f32x4*)(sc + ob);
        const f32x4 b4 = *(const f32x4*)(bs + ob);
        #pragma unroll
        for (int r = 0; r < 4; ++r) {
            float* orow = out + outbase + (((size_t)(ob + r)) << 10)
                        + hw0 + wn * 64 + lr;
            #pragma unroll
            for (int j = 0; j < 4; ++j) {
                float v = acc[i][j][r] * s4[r] + b4[r];
                // mish(v) = v * t(t+2)/(t(t+2)+2), t = e^v
                float e   = __expf(fminf(v, 15.0f));
                float num = e * (e + 2.0f);
                orow[j * 16] = v * (num / (num + 2.0f));
            }
        }
    }
}

// ---------- SPP pools: m5=pool5(y), m9=pool5(m5), m13=pool5(m9) ----------
// XCD-affinity: id&7 = b>>1, matching the GEMM swizzle. 2 channels per block.
__global__ __launch_bounds__(256) void pool_kernel(float* __restrict__ out)
{
    __shared__ float A[32][33];
    __shared__ float B[32][33];
    const int t  = threadIdx.x;
    const int id = blockIdx.x;        // 0..4095
    const int x8 = id & 7;
    const int j  = id >> 3;           // 0..511
    const int b  = 2 * x8 + (j >> 8);
    const int o2 = (j & 255) * 2;
    const int r  = t >> 3;            // row 0..31
    const int c0 = (t & 7) * 4;       // col base

    for (int ci = 0; ci < 2; ++ci) {
        const int o = o2 + ci;
        const size_t ybase = ((size_t)(b * 2048 + 1536 + o)) << 10;
        f32x4 v = *(const f32x4*)(out + ybase + t * 4);
        A[r][c0] = v[0]; A[r][c0 + 1] = v[1]; A[r][c0 + 2] = v[2]; A[r][c0 + 3] = v[3];
        __syncthreads();

        for (int p = 0; p < 3; ++p) {
            float wv[8];
            #pragma unroll
            for (int k = 0; k < 8; ++k) {
                int cc = c0 - 2 + k;
                wv[k] = (cc >= 0 && cc < 32) ? A[r][cc] : -INFINITY;
            }
            #pragma unroll
            for (int q = 0; q < 4; ++q) {
                float h = fmaxf(fmaxf(fmaxf(wv[q], wv[q + 1]), fmaxf(wv[q + 2], wv[q + 3])), wv[q + 4]);
                B[r][c0 + q] = h;
            }
            __syncthreads();
            f32x4 m;
            m[0] = m[1] = m[2] = m[3] = -INFINITY;
            #pragma unroll
            for (int k = 0; k < 5; ++k) {
                int rr = r - 2 + k;
                if (rr >= 0 && rr < 32) {
                    m[0] = fmaxf(m[0], B[rr][c0]);
                    m[1] = fmaxf(m[1], B[rr][c0 + 1]);
                    m[2] = fmaxf(m[2], B[rr][c0 + 2]);
                    m[3] = fmaxf(m[3], B[rr][c0 + 3]);
                }
            }
            A[r][c0] = m[0]; A[r][c0 + 1] = m[1]; A[r][c0 + 2] = m[2]; A[r][c0 + 3] = m[3];
            const size_t obase = ((size_t)(b * 2048 + (2 - p) * 512 + o)) << 10;
            *(f32x4*)(out + obase + t * 4) = m;
            __syncthreads();
        }
    }
}

extern "C" void kernel_launch(void* const* d_in, const int* in_sizes, int n_in,
                              void* d_out, int out_size, void* d_ws, size_t ws_size,
                              hipStream_t stream)
{
    const float* x     = (const float*)d_in[0];  // [16,1024,32,32]
    const float* W     = (const float*)d_in[1];  // [512,1024]
    const float* gamma = (const float*)d_in[2];
    const float* beta  = (const float*)d_in[3];
    const float* rmean = (const float*)d_in[4];
    const float* rvar  = (const float*)d_in[5];
    float* out = (float*)d_out;                  // [16,2048,32,32]
    char*  ws  = (char*)d_ws;

    __bf16* Wb = (__bf16*)ws;                    // 1048576 B: [512][1024]
    float*  sc = (float*)(ws + 1048576);         //    2048 B
    float*  bs = (float*)(ws + 1050624);         //    2048 B

    prep_kernel<<<512, 256, 0, stream>>>(W, gamma, beta, rmean, rvar, Wb, sc, bs);
    gemm_kernel<<<dim3(4, 8, 16), 256, 0, stream>>>(Wb, x, sc, bs, out);
    pool_kernel<<<4096, 256, 0, stream>>>(out);
}